// Round 7
// baseline (393.117 us; speedup 1.0000x reference)
//
#include <hip/hip_runtime.h>
#include <stdint.h>

// Problem constants (B=4, C=256, H=W=64, PATCH=3, STRIDE=1)
#define NP   3844   // 62*62 patches == per-batch feat pixels
#define ND   62
#define NC   256
#define HW   64
#define SP   4096   // 64*64 pixels per image
#define SPSP ((size_t)SP * SP)      // G elements per batch
#define NCSP ((size_t)NC * SP)      // panel elements per batch
#define EPS_G 0.15f        // margin: MFMA fp32 accum + stencil adds + subnormals
#define HULP 0.00390625f   // half-ulp factor for bf16 store (2^-8)
#define SPLIT_REL 0.0009765625f  // 2^-10: fp16 quantization of both operands

typedef __attribute__((ext_vector_type(8))) short short8;
typedef __attribute__((ext_vector_type(8))) unsigned short ushort8;
typedef __attribute__((ext_vector_type(8))) _Float16 half8;
typedef __attribute__((ext_vector_type(4))) float float4v;
typedef unsigned long long u64;

__device__ __forceinline__ unsigned int orderf(float v) {
    unsigned int u = __float_as_uint(v);
    return (u & 0x80000000u) ? ~u : (u | 0x80000000u);
}
__device__ __forceinline__ float unorderf(unsigned int k) {
    return __uint_as_float((k & 0x80000000u) ? (k ^ 0x80000000u) : ~k);
}
__device__ __forceinline__ float bf2f(unsigned short h) {
    return __uint_as_float(((unsigned int)h) << 16);
}
__device__ __forceinline__ unsigned short f2bf_rne(float a) {
    unsigned ua = __float_as_uint(a);
    return (unsigned short)((ua + 0x7fffu + ((ua >> 16) & 1u)) >> 16);
}

// ---------------------------------------------------------------------------
// Kernel 0: style_t[s][c] = style[c][s]  (4 MB fp32, for coalesced c-reads)
// ---------------------------------------------------------------------------
__global__ __launch_bounds__(256) void transpose_style(
    const float* __restrict__ style, float* __restrict__ style_t)
{
    __shared__ float t[32][33];
    const int s0 = blockIdx.x * 32;
    const int c0 = blockIdx.y * 32;
    const int col = threadIdx.x & 31, r8 = threadIdx.x >> 5;
    #pragma unroll
    for (int i = 0; i < 4; ++i) {
        int r = r8 + i * 8;
        t[r][col] = style[(size_t)(c0 + r) * SP + s0 + col];
    }
    __syncthreads();
    #pragma unroll
    for (int i = 0; i < 4; ++i) {
        int r = r8 + i * 8;
        style_t[(size_t)(s0 + r) * 256 + c0 + col] = t[col][r];
    }
}

// ---------------------------------------------------------------------------
// Kernel 0b: column L2 norms over c: na_c[b][s], nb_s[t]  (Cauchy-Schwarz bound)
// blocks 0..63: content (b = blk>>4, s-chunk = blk&15); 64..79: style.
// ---------------------------------------------------------------------------
__global__ __launch_bounds__(256) void col_norms(
    const float* __restrict__ content, const float* __restrict__ style,
    float* __restrict__ na_c, float* __restrict__ nb_s)
{
    const int blk = blockIdx.x, tid = threadIdx.x;
    const float* src;
    float* dst;
    int s;
    if (blk < 64) {
        int b = blk >> 4, ch = blk & 15;
        src = content + (size_t)b * NCSP;
        dst = na_c + b * SP;
        s = ch * 256 + tid;
    } else {
        src = style;
        dst = nb_s;
        s = (blk - 64) * 256 + tid;
    }
    float sum = 0.f;
    #pragma unroll 4
    for (int c = 0; c < NC; ++c) {
        float v = src[(size_t)c * SP + s];
        sum = fmaf(v, v, sum);
    }
    dst[s] = sqrtf(sum);
}

// ---------------------------------------------------------------------------
// Kernel 0c: fp32 [256][4096] -> fp16 (RNE) in k-panel layout, batched over z.
// P[kp][s][j], kp=k/8: one MFMA fragment = 8 halves at ((kp*4096+s)*8).
// ---------------------------------------------------------------------------
__global__ __launch_bounds__(256) void panels_f16(
    const float* __restrict__ src0, unsigned short* __restrict__ P0)
{
    const float* src = src0 + (size_t)blockIdx.z * NCSP;
    unsigned short* P = P0 + (size_t)blockIdx.z * NCSP;

    __shared__ unsigned short buf[512 * 8];
    const int kp = blockIdx.x;            // 0..31
    const int s0 = blockIdx.y * 512;      // 0..7
    const int tid = threadIdx.x;
    #pragma unroll
    for (int kk = 0; kk < 8; ++kk) {
        #pragma unroll
        for (int h = 0; h < 2; ++h) {
            int s = tid + h * 256;
            float a = src[(size_t)(kp * 8 + kk) * SP + s0 + s];
            _Float16 hf = (_Float16)a;    // RNE
            unsigned short hb;
            __builtin_memcpy(&hb, &hf, 2);
            buf[s * 8 + kk] = hb;
        }
    }
    __syncthreads();
    #pragma unroll
    for (int h = 0; h < 2; ++h) {
        int s = tid + h * 256;
        size_t o = ((size_t)kp * 4096 + s0 + s) * 8;
        *(ushort8*)(P + o) = *(const ushort8*)(buf + s * 8);
    }
}

// ---------------------------------------------------------------------------
// Kernel 1: fp16 single-MFMA panel GEMM — G = content^T * style, batched z.
// Same addressing as the validated bf16 panel GEMM; 1/3 the MFMA work.
// ---------------------------------------------------------------------------
__global__ __launch_bounds__(256) void g_gemm_f16(
    const unsigned short* __restrict__ A0,
    const unsigned short* __restrict__ B,
    unsigned short* __restrict__ G0)
{
    const unsigned short* A = A0 + (size_t)blockIdx.z * NCSP;
    unsigned short* Gb = G0 + (size_t)blockIdx.z * SPSP;

    const int tid  = threadIdx.x;
    const int s0   = blockIdx.x * 128;
    const int t0   = blockIdx.y * 128;
    const int wave = tid >> 6, lane = tid & 63;
    const int wm = (wave >> 1) * 64, wn = (wave & 1) * 64;
    const int fr = lane & 15;
    const int fq = lane >> 4;     // k-quad -> panel offset

    float4v acc[4][4];
    #pragma unroll
    for (int i = 0; i < 4; ++i)
        #pragma unroll
        for (int j = 0; j < 4; ++j) acc[i][j] = (float4v)(0.f);

    size_t ra0[4], rb0[4];
    #pragma unroll
    for (int f = 0; f < 4; ++f) {
        ra0[f] = ((size_t)fq * 4096 + s0 + wm + f * 16 + fr) * 8;
        rb0[f] = ((size_t)fq * 4096 + t0 + wn + f * 16 + fr) * 8;
    }

    #pragma unroll 2
    for (int ks = 0; ks < 8; ++ks) {
        const size_t pan = (size_t)ks * 4 * 4096 * 8;
        half8 a[4], b[4];
        #pragma unroll
        for (int f = 0; f < 4; ++f) {
            a[f] = *(const half8*)(A + pan + ra0[f]);
            b[f] = *(const half8*)(B + pan + rb0[f]);
        }
        #pragma unroll
        for (int fm = 0; fm < 4; ++fm)
            #pragma unroll
            for (int fn = 0; fn < 4; ++fn)
                acc[fm][fn] = __builtin_amdgcn_mfma_f32_16x16x32_f16(
                    a[fm], b[fn], acc[fm][fn], 0, 0, 0);
    }

    // store: C/D layout col=lane&15, row=(lane>>4)*4+reg  (validated)
    #pragma unroll
    for (int fm = 0; fm < 4; ++fm)
        #pragma unroll
        for (int fn = 0; fn < 4; ++fn)
            #pragma unroll
            for (int r = 0; r < 4; ++r) {
                unsigned short o = f2bf_rne(acc[fm][fn][r]);
                Gb[(size_t)(s0 + wm + fm * 16 + fq * 4 + r) * SP + t0 + wn + fn * 16 + fr] = o;
            }
}

// ---------------------------------------------------------------------------
// Kernel 1-fallback (round-3..6 validated): LDS-staged bf16x3 GEMM (fp32 in)
// ---------------------------------------------------------------------------
__global__ __launch_bounds__(256, 2) void g_gemm(
    const float* __restrict__ contentb,
    const float* __restrict__ style,
    unsigned short* __restrict__ Gb)
{
    __shared__ __attribute__((aligned(16))) short Ah[4 * 128 * 8];
    __shared__ __attribute__((aligned(16))) short Al[4 * 128 * 8];
    __shared__ __attribute__((aligned(16))) short Bh[4 * 128 * 8];
    __shared__ __attribute__((aligned(16))) short Bl[4 * 128 * 8];

    const int tid  = threadIdx.x;
    const int s0   = blockIdx.x * 128;
    const int t0   = blockIdx.y * 128;
    const int wave = tid >> 6, lane = tid & 63;
    const int wm = (wave >> 1) * 64, wn = (wave & 1) * 64;
    const int fr = lane & 15;
    const int fq = lane >> 4;
    const int sm = tid & 127;
    const int sl = tid >> 7;

    float4v acc[4][4];
    #pragma unroll
    for (int i = 0; i < 4; ++i)
        #pragma unroll
        for (int j = 0; j < 4; ++j) acc[i][j] = (float4v)(0.f);

    for (int k0 = 0; k0 < 256; k0 += 32) {
        __syncthreads();
        #pragma unroll
        for (int h = 0; h < 2; ++h) {
            const float* src = h ? style : contentb;
            const int rb = h ? t0 : s0;
            short* dh = h ? Bh : Ah;
            short* dl = h ? Bl : Al;
            float v[16];
            #pragma unroll
            for (int j = 0; j < 16; ++j)
                v[j] = src[(size_t)(k0 + sl * 16 + j) * SP + rb + sm];
            short8 h0, h1, l0, l1;
            #pragma unroll
            for (int j = 0; j < 8; ++j) {
                unsigned ua = __float_as_uint(v[j]);
                unsigned ub = __float_as_uint(v[j + 8]);
                h0[j] = (short)(ua >> 16);
                h1[j] = (short)(ub >> 16);
                float ra  = v[j]     - __uint_as_float(ua & 0xffff0000u);
                float rb2 = v[j + 8] - __uint_as_float(ub & 0xffff0000u);
                l0[j] = (short)(__float_as_uint(ra) >> 16);
                l1[j] = (short)(__float_as_uint(rb2) >> 16);
            }
            *(short8*)(dh + ((sl * 2)     * 128 + sm) * 8) = h0;
            *(short8*)(dh + ((sl * 2 + 1) * 128 + sm) * 8) = h1;
            *(short8*)(dl + ((sl * 2)     * 128 + sm) * 8) = l0;
            *(short8*)(dl + ((sl * 2 + 1) * 128 + sm) * 8) = l1;
        }
        __syncthreads();

        short8 ah[4], al[4], bh[4], bl[4];
        #pragma unroll
        for (int f = 0; f < 4; ++f) {
            const int ra = (fq * 128 + wm + f * 16 + fr) * 8;
            const int rb = (fq * 128 + wn + f * 16 + fr) * 8;
            ah[f] = *(const short8*)(Ah + ra);
            al[f] = *(const short8*)(Al + ra);
            bh[f] = *(const short8*)(Bh + rb);
            bl[f] = *(const short8*)(Bl + rb);
        }
        #pragma unroll
        for (int fm = 0; fm < 4; ++fm)
            #pragma unroll
            for (int fn = 0; fn < 4; ++fn) {
                acc[fm][fn] = __builtin_amdgcn_mfma_f32_16x16x32_bf16(ah[fm], bh[fn], acc[fm][fn], 0, 0, 0);
                acc[fm][fn] = __builtin_amdgcn_mfma_f32_16x16x32_bf16(ah[fm], bl[fn], acc[fm][fn], 0, 0, 0);
                acc[fm][fn] = __builtin_amdgcn_mfma_f32_16x16x32_bf16(al[fm], bh[fn], acc[fm][fn], 0, 0, 0);
            }
    }

    #pragma unroll
    for (int fm = 0; fm < 4; ++fm)
        #pragma unroll
        for (int fn = 0; fn < 4; ++fn)
            #pragma unroll
            for (int r = 0; r < 4; ++r) {
                unsigned short o = f2bf_rne(acc[fm][fn][r]);
                Gb[(size_t)(s0 + wm + fm * 16 + fq * 4 + r) * SP + t0 + wn + fn * 16 + fr] = o;
            }
}

// ---------------------------------------------------------------------------
// Kernel 2: stencil, 4 q's (consecutive x, same y) per wave — 6 shared
// row-windows per (it,u) instead of 12. Same validated shift-extraction.
// Grid: (248, nb). wave-unit id = blockIdx.x*4+wave in [0,992): y=id>>4, x0=(id&15)*4.
// ---------------------------------------------------------------------------
__global__ __launch_bounds__(256) void stencil4(
    const unsigned short* __restrict__ G0,
    const float* __restrict__ enc_bias,
    u64* __restrict__ cand2, int bbase)
{
    const int bl = blockIdx.y;
    const unsigned short* G = G0 + (size_t)bl * SPSP;
    const int b = bbase + bl;

    const int wid = blockIdx.x * 4 + (threadIdx.x >> 6);   // 0..991
    const int lane = threadIdx.x & 63;
    const int y = wid >> 4;
    const int x0 = (wid & 15) * 4;
    const int jg = (lane & 7) * 8;
    const int ig = lane >> 3;

    u64 k1[4] = {0, 0, 0, 0}, k2[4] = {0, 0, 0, 0};

    for (int it = 0; it < 8; ++it) {
        const int i = it * 8 + ig;
        if (i <= 61) {
            float f[4][8];
            #pragma unroll
            for (int qk = 0; qk < 4; ++qk)
                #pragma unroll
                for (int j = 0; j < 8; ++j) f[qk][j] = 0.f;

            #pragma unroll
            for (int u = 0; u < 3; ++u) {
                const unsigned short* rbase =
                    G + ((size_t)(y + u) * 64 + x0) * SP + (size_t)(i + u) * 64 + jg;
                ushort8 w[6]; unsigned e[6];
                #pragma unroll
                for (int dd = 0; dd < 6; ++dd) {
                    const unsigned short* rp = rbase + (size_t)dd * SP;
                    w[dd] = *(const ushort8*)rp;
                    e[dd] = (jg < 56) ? *(const unsigned*)(rp + 8) : 0u;
                }
                #pragma unroll
                for (int qk = 0; qk < 4; ++qk) {
                    #pragma unroll
                    for (int v = 0; v < 3; ++v) {
                        const int dd = qk + v;
                        float w8 = bf2f((unsigned short)(e[dd] & 0xffffu));
                        float w9 = bf2f((unsigned short)(e[dd] >> 16));
                        if (v == 0) {
                            #pragma unroll
                            for (int j = 0; j < 8; ++j) f[qk][j] += bf2f(w[dd][j]);
                        } else if (v == 1) {
                            #pragma unroll
                            for (int j = 0; j < 7; ++j) f[qk][j] += bf2f(w[dd][j + 1]);
                            f[qk][7] += w8;
                        } else {
                            #pragma unroll
                            for (int j = 0; j < 6; ++j) f[qk][j] += bf2f(w[dd][j + 2]);
                            f[qk][6] += w8;
                            f[qk][7] += w9;
                        }
                    }
                }
            }
            #pragma unroll
            for (int qk = 0; qk < 4; ++qk) {
                if (x0 + qk > 61) continue;   // wave-uniform
                #pragma unroll
                for (int j = 0; j < 8; ++j) {
                    int jj = jg + j;
                    if (jj <= 61) {
                        int p = i * ND + jj;
                        float fv = f[qk][j] + enc_bias[p];
                        u64 key = ((u64)orderf(fv) << 32) | (unsigned)(NP - 1 - p);
                        if (key > k1[qk]) { k2[qk] = k1[qk]; k1[qk] = key; }
                        else if (key > k2[qk]) k2[qk] = key;
                    }
                }
            }
        }
    }

    #pragma unroll
    for (int qk = 0; qk < 4; ++qk) {
        const int x = x0 + qk;
        if (x > 61) continue;   // wave-uniform
        u64 a1 = k1[qk], a2 = k2[qk];
        #pragma unroll
        for (int d = 1; d < 64; d <<= 1) {
            u64 o1 = __shfl_xor(a1, d, 64);
            u64 o2 = __shfl_xor(a2, d, 64);
            u64 hi = a1 > o1 ? a1 : o1;
            u64 lo = a1 > o1 ? o1 : a1;
            u64 m2 = a2 > o2 ? a2 : o2;
            a1 = hi;
            a2 = lo > m2 ? lo : m2;
        }
        if (lane == 0) {
            size_t o = (size_t)(b * NP + y * ND + x) * 2;
            cand2[o] = a1;
            cand2[o + 1] = a2;
        }
    }
}

// ---------------------------------------------------------------------------
// Kernel 3: skip bound = sum_9 [halfulp(G_d) + 2^-10*na*nb] per candidate,
// + EPS_G; exact fp32 rescore of survivors (validated pattern).
// ---------------------------------------------------------------------------
__global__ __launch_bounds__(128) void rescore5(
    const float* __restrict__ content,
    const float* __restrict__ style_t,   // [s][c]
    const float* __restrict__ enc_bias,
    const unsigned short* __restrict__ G0,
    const float* __restrict__ na_c,      // [4][4096]
    const float* __restrict__ nb_s,      // [4096]
    const u64* __restrict__ cand2,
    int* __restrict__ idx, int bbase)
{
    __shared__ float sc[2];
    __shared__ int   pp[2];
    const int bl = blockIdx.x / NP;
    const int q  = blockIdx.x - bl * NP;
    const int b  = bbase + bl;
    const int qa = b * NP + q;
    const unsigned short* G = G0 + (size_t)bl * SPSP;
    const int tid = threadIdx.x;
    const int wave = tid >> 6, lane = tid & 63;
    const int y = q / ND, x = q - y * ND;

    const u64 k1 = cand2[(size_t)qa * 2];
    const u64 k2 = cand2[(size_t)qa * 2 + 1];
    const int p1 = NP - 1 - (int)(k1 & 0xffffffffu);
    const int p2 = NP - 1 - (int)(k2 & 0xffffffffu);
    const float f1 = unorderf((unsigned int)(k1 >> 32));
    const float f2 = unorderf((unsigned int)(k2 >> 32));

    if (k2 == 0ull) {
        if (tid == 0) idx[qa] = p1;
        return;
    }

    // per-candidate screening bound
    float eul = 0.f;
    {
        const int side = lane >> 4;            // lanes 0-8 -> p1, 16-24 -> p2
        const int d = lane & 15;
        if (side < 2 && d < 9) {
            int u = d / 3, v = d - u * 3;
            int pc = side ? p2 : p1;
            int pi = pc / ND, pj = pc - pi * ND;
            int sd = (y + u) * 64 + (x + v);
            int td = (pi + u) * 64 + (pj + v);
            unsigned short g = G[(size_t)sd * SP + td];
            float gf = bf2f(g);
            float hulp = __uint_as_float(__float_as_uint(gf) & 0x7f800000u) * HULP;
            eul = hulp + SPLIT_REL * na_c[b * SP + sd] * nb_s[td];
        }
    }
    #pragma unroll
    for (int d = 1; d < 64; d <<= 1) eul += __shfl_xor(eul, d, 64);
    // eul now = E(p1) + E(p2) on every lane

    if ((f1 - f2) > eul + EPS_G) {
        if (tid == 0) idx[qa] = p1;
        return;
    }

    const int pc = wave ? p2 : p1;
    const int pi = pc / ND, pj = pc - pi * ND;
    const int off_c = y * 64 + x;
    const int off_s = pi * 64 + pj;
    float s = 0.f;
    #pragma unroll
    for (int g = 0; g < 4; ++g) {
        const int c = g * 64 + lane;
        const float* cw = content + ((size_t)b * NC + c) * SP + off_c;
        const float* sw = style_t + (size_t)off_s * 256 + c;
        #pragma unroll
        for (int u = 0; u < 3; ++u)
            #pragma unroll
            for (int v = 0; v < 3; ++v)
                s = fmaf(cw[u * 64 + v], sw[(size_t)(u * 64 + v) * 256], s);
    }
    #pragma unroll
    for (int d = 32; d; d >>= 1) s += __shfl_xor(s, d, 64);
    if (lane == 0) { sc[wave] = s + enc_bias[pc]; pp[wave] = pc; }
    __syncthreads();
    if (tid == 0) {
        float s0 = sc[0], s1 = sc[1];
        int q0 = pp[0], q1 = pp[1];
        idx[qa] = (s1 > s0 || (s1 == s0 && q1 < q0)) ? q1 : q0;
    }
}

// ---------------------------------------------------------------------------
// Kernel 4: output via style_t with LDS row accumulation (validated)
// ---------------------------------------------------------------------------
__global__ __launch_bounds__(256) void produce_out2(
    const float* __restrict__ style_t,
    const float* __restrict__ dec_bias,
    const float* __restrict__ intra_bias,
    const int* __restrict__ idx,
    float* __restrict__ out)
{
    __shared__ float orow[64][129];
    __shared__ int pidx[3][ND];

    const int bh = blockIdx.x;
    const int b = bh >> 6, h = bh & 63;
    const int ch = blockIdx.y;
    const int tid = threadIdx.x;

    if (tid < 3 * ND) {
        int u = tid / ND, xx = tid - u * ND;
        int yy = h - u;
        pidx[u][xx] = (yy >= 0 && yy < ND) ? idx[b * NP + yy * ND + xx] : 0;
    }
    for (int i = tid; i < 64 * 129; i += 256) ((float*)orow)[i] = 0.f;
    __syncthreads();

    const int cl = tid & 127;
    const int xo = tid >> 7;
    for (int u = 0; u < 3; ++u) {
        int yy = h - u;
        if (yy < 0 || yy >= ND) continue;
        #pragma unroll
        for (int v = 0; v < 3; ++v) {
            for (int xi = (xo + v) & 1; xi < ND; xi += 2) {
                int p = pidx[u][xi];
                int pi = p / ND, pj = p - pi * ND;
                float sv = style_t[(size_t)(pi * 64 + pj + u * 64 + v) * 256 + ch * 128 + cl];
                orow[xi + v][cl] += sv;
            }
        }
    }
    __syncthreads();

    const int w = tid & 63, cg = tid >> 6;
    const int cu  = (h < 2 ? h : 2) - (h > 61 ? h - 61 : 0) + 1;
    const int cvw = (w < 2 ? w : 2) - (w > 61 ? w - 61 : 0) + 1;
    const float cnt = (float)(cu * cvw);
    #pragma unroll 4
    for (int ci = 0; ci < 32; ++ci) {
        int cll = cg * 32 + ci;
        int c = ch * 128 + cll;
        float val = (orow[w][cll] + dec_bias[c]) / (cnt + intra_bias[c]);
        out[(((size_t)b * NC + c) * 64 + h) * 64 + w] = val;
    }
}

// ---------------------------------------------------------------------------
extern "C" void kernel_launch(void* const* d_in, const int* in_sizes, int n_in,
                              void* d_out, int out_size, void* d_ws, size_t ws_size,
                              hipStream_t stream) {
    const float* content    = (const float*)d_in[0];
    const float* style      = (const float*)d_in[1];
    const float* enc_bias   = (const float*)d_in[2];
    const float* dec_bias   = (const float*)d_in[3];
    const float* intra_bias = (const float*)d_in[4];
    float* out = (float*)d_out;

    const size_t G_BYTES     = SPSP * 2;                   //  33,554,432
    const size_t CAND2_BYTES = (size_t)4 * NP * 2 * 8;     //     246,016
    const size_t IDX_BYTES   = (size_t)4 * NP * 4;         //      61,504
    const size_t ST_BYTES    = NCSP * 16;                  //   4,194,304
    const size_t P16_BYTES   = NCSP * 2;                   //   2,097,152
    const size_t NA_BYTES    = (size_t)4 * SP * 4;         //      65,536
    const size_t NB_BYTES    = (size_t)SP * 4;             //      16,384

    // Tier A layout (4 G's resident + fp16 panels + norms): ~142 MB
    const size_t A_OFF_CAND2 = 4 * G_BYTES;
    const size_t A_OFF_IDX   = A_OFF_CAND2 + CAND2_BYTES;
    const size_t A_OFF_ST    = A_OFF_IDX + IDX_BYTES;
    const size_t A_OFF_PS    = A_OFF_ST + ST_BYTES;
    const size_t A_OFF_PC    = A_OFF_PS + P16_BYTES;
    const size_t A_OFF_NA    = A_OFF_PC + 4 * P16_BYTES;
    const size_t A_OFF_NB    = A_OFF_NA + NA_BYTES;
    const size_t NEED_A      = A_OFF_NB + NB_BYTES;        // 149,287,232

    // Tier B layout (single G, bf16x3 fp32-input GEMM): ~38.1 MB
    const size_t B_OFF_CAND2 = G_BYTES;
    const size_t B_OFF_IDX   = B_OFF_CAND2 + CAND2_BYTES;
    const size_t B_OFF_ST    = B_OFF_IDX + IDX_BYTES;
    const size_t B_OFF_NA    = B_OFF_ST + ST_BYTES;
    const size_t B_OFF_NB    = B_OFF_NA + NA_BYTES;
    const size_t NEED_B      = B_OFF_NB + NB_BYTES;        // 38,138,176
    (void)NEED_B;

    if (ws_size >= NEED_A) {
        unsigned short* G4 = (unsigned short*)d_ws;
        u64* cand2     = (u64*)((char*)d_ws + A_OFF_CAND2);
        int* idx       = (int*)((char*)d_ws + A_OFF_IDX);
        float* style_t = (float*)((char*)d_ws + A_OFF_ST);
        unsigned short* PS = (unsigned short*)((char*)d_ws + A_OFF_PS);
        unsigned short* PC = (unsigned short*)((char*)d_ws + A_OFF_PC);
        float* na_c    = (float*)((char*)d_ws + A_OFF_NA);
        float* nb_s    = (float*)((char*)d_ws + A_OFF_NB);

        transpose_style<<<dim3(128, 8), 256, 0, stream>>>(style, style_t);
        col_norms<<<dim3(80), 256, 0, stream>>>(content, style, na_c, nb_s);
        panels_f16<<<dim3(32, 8, 1), 256, 0, stream>>>(style, PS);
        panels_f16<<<dim3(32, 8, 4), 256, 0, stream>>>(content, PC);
        g_gemm_f16<<<dim3(32, 32, 4), 256, 0, stream>>>(PC, PS, G4);
        stencil4<<<dim3(248, 4), 256, 0, stream>>>(G4, enc_bias, cand2, 0);
        rescore5<<<dim3(4 * NP), 128, 0, stream>>>(
            content, style_t, enc_bias, G4, na_c, nb_s, cand2, idx, 0);
        produce_out2<<<dim3(4 * 64, 2), 256, 0, stream>>>(
            style_t, dec_bias, intra_bias, idx, out);
    } else {
        unsigned short* Gb = (unsigned short*)d_ws;
        u64* cand2     = (u64*)((char*)d_ws + B_OFF_CAND2);
        int* idx       = (int*)((char*)d_ws + B_OFF_IDX);
        float* style_t = (float*)((char*)d_ws + B_OFF_ST);
        float* na_c    = (float*)((char*)d_ws + B_OFF_NA);
        float* nb_s    = (float*)((char*)d_ws + B_OFF_NB);

        transpose_style<<<dim3(128, 8), 256, 0, stream>>>(style, style_t);
        col_norms<<<dim3(80), 256, 0, stream>>>(content, style, na_c, nb_s);
        for (int b = 0; b < 4; ++b) {
            g_gemm<<<dim3(32, 32), 256, 0, stream>>>(
                content + (size_t)b * NCSP, style, Gb);
            stencil4<<<dim3(248, 1), 256, 0, stream>>>(Gb, enc_bias, cand2, b);
            rescore5<<<dim3(NP), 128, 0, stream>>>(
                content, style_t, enc_bias, Gb, na_c, nb_s, cand2, idx, b);
        }
        produce_out2<<<dim3(4 * 64, 2), 256, 0, stream>>>(
            style_t, dec_bias, intra_bias, idx, out);
    }
}

// Round 8
// 319.458 us; speedup vs baseline: 1.2306x; 1.2306x over previous
//
#include <hip/hip_runtime.h>
#include <stdint.h>

// Problem constants (B=4, C=256, H=W=64, PATCH=3, STRIDE=1)
#define NP   3844   // 62*62 patches == per-batch feat pixels
#define ND   62
#define NC   256
#define HW   64
#define SP   4096   // 64*64 pixels per image
#define SPSP ((size_t)SP * SP)      // G elements per batch
#define NCSP ((size_t)NC * SP)      // panel elements per batch
#define EPS_G 0.15f        // margin: MFMA fp32 accum + stencil adds + subnormals
#define HULP 0.00390625f   // half-ulp factor for bf16 store (2^-8)
#define SPLIT_REL 0.0009765625f  // 2^-10: fp16 quantization of both operands

typedef __attribute__((ext_vector_type(8))) short short8;
typedef __attribute__((ext_vector_type(8))) unsigned short ushort8;
typedef __attribute__((ext_vector_type(8))) _Float16 half8;
typedef __attribute__((ext_vector_type(4))) float float4v;
typedef unsigned long long u64;

__device__ __forceinline__ unsigned int orderf(float v) {
    unsigned int u = __float_as_uint(v);
    return (u & 0x80000000u) ? ~u : (u | 0x80000000u);
}
__device__ __forceinline__ float unorderf(unsigned int k) {
    return __uint_as_float((k & 0x80000000u) ? (k ^ 0x80000000u) : ~k);
}
__device__ __forceinline__ float bf2f(unsigned short h) {
    return __uint_as_float(((unsigned int)h) << 16);
}
__device__ __forceinline__ unsigned short f2bf_rne(float a) {
    unsigned ua = __float_as_uint(a);
    return (unsigned short)((ua + 0x7fffu + ((ua >> 16) & 1u)) >> 16);
}

// ---------------------------------------------------------------------------
// Kernel 0: batched [256][4096] -> [4096][256] fp32 transpose (style z=1,
// content z=4). Coalesced via 32x32 LDS tile.
// ---------------------------------------------------------------------------
__global__ __launch_bounds__(256) void transpose_b(
    const float* __restrict__ src0, float* __restrict__ dst0)
{
    const float* src = src0 + (size_t)blockIdx.z * NCSP;
    float* dst = dst0 + (size_t)blockIdx.z * NCSP;
    __shared__ float t[32][33];
    const int s0 = blockIdx.x * 32;
    const int c0 = blockIdx.y * 32;
    const int col = threadIdx.x & 31, r8 = threadIdx.x >> 5;
    #pragma unroll
    for (int i = 0; i < 4; ++i) {
        int r = r8 + i * 8;
        t[r][col] = src[(size_t)(c0 + r) * SP + s0 + col];
    }
    __syncthreads();
    #pragma unroll
    for (int i = 0; i < 4; ++i) {
        int r = r8 + i * 8;
        dst[(size_t)(s0 + r) * 256 + c0 + col] = t[col][r];
    }
}

// ---------------------------------------------------------------------------
// Kernel 0b: column L2 norms over c: na_c[b][s], nb_s[t]  (Cauchy-Schwarz bound)
// ---------------------------------------------------------------------------
__global__ __launch_bounds__(256) void col_norms(
    const float* __restrict__ content, const float* __restrict__ style,
    float* __restrict__ na_c, float* __restrict__ nb_s)
{
    const int blk = blockIdx.x, tid = threadIdx.x;
    const float* src;
    float* dst;
    int s;
    if (blk < 64) {
        int b = blk >> 4, ch = blk & 15;
        src = content + (size_t)b * NCSP;
        dst = na_c + b * SP;
        s = ch * 256 + tid;
    } else {
        src = style;
        dst = nb_s;
        s = (blk - 64) * 256 + tid;
    }
    float sum = 0.f;
    #pragma unroll 4
    for (int c = 0; c < NC; ++c) {
        float v = src[(size_t)c * SP + s];
        sum = fmaf(v, v, sum);
    }
    dst[s] = sqrtf(sum);
}

// ---------------------------------------------------------------------------
// Kernel 0c: fp32 [256][4096] -> fp16 (RNE) in k-panel layout, batched over z.
// ---------------------------------------------------------------------------
__global__ __launch_bounds__(256) void panels_f16(
    const float* __restrict__ src0, unsigned short* __restrict__ P0)
{
    const float* src = src0 + (size_t)blockIdx.z * NCSP;
    unsigned short* P = P0 + (size_t)blockIdx.z * NCSP;

    __shared__ unsigned short buf[512 * 8];
    const int kp = blockIdx.x;            // 0..31
    const int s0 = blockIdx.y * 512;      // 0..7
    const int tid = threadIdx.x;
    #pragma unroll
    for (int kk = 0; kk < 8; ++kk) {
        #pragma unroll
        for (int h = 0; h < 2; ++h) {
            int s = tid + h * 256;
            float a = src[(size_t)(kp * 8 + kk) * SP + s0 + s];
            _Float16 hf = (_Float16)a;    // RNE
            unsigned short hb;
            __builtin_memcpy(&hb, &hf, 2);
            buf[s * 8 + kk] = hb;
        }
    }
    __syncthreads();
    #pragma unroll
    for (int h = 0; h < 2; ++h) {
        int s = tid + h * 256;
        size_t o = ((size_t)kp * 4096 + s0 + s) * 8;
        *(ushort8*)(P + o) = *(const ushort8*)(buf + s * 8);
    }
}

// ---------------------------------------------------------------------------
// Kernel 1: fp16 single-MFMA panel GEMM — G = content^T * style, batched z.
// (round-7 validated)
// ---------------------------------------------------------------------------
__global__ __launch_bounds__(256) void g_gemm_f16(
    const unsigned short* __restrict__ A0,
    const unsigned short* __restrict__ B,
    unsigned short* __restrict__ G0)
{
    const unsigned short* A = A0 + (size_t)blockIdx.z * NCSP;
    unsigned short* Gb = G0 + (size_t)blockIdx.z * SPSP;

    const int tid  = threadIdx.x;
    const int s0   = blockIdx.x * 128;
    const int t0   = blockIdx.y * 128;
    const int wave = tid >> 6, lane = tid & 63;
    const int wm = (wave >> 1) * 64, wn = (wave & 1) * 64;
    const int fr = lane & 15;
    const int fq = lane >> 4;     // k-quad -> panel offset

    float4v acc[4][4];
    #pragma unroll
    for (int i = 0; i < 4; ++i)
        #pragma unroll
        for (int j = 0; j < 4; ++j) acc[i][j] = (float4v)(0.f);

    size_t ra0[4], rb0[4];
    #pragma unroll
    for (int f = 0; f < 4; ++f) {
        ra0[f] = ((size_t)fq * 4096 + s0 + wm + f * 16 + fr) * 8;
        rb0[f] = ((size_t)fq * 4096 + t0 + wn + f * 16 + fr) * 8;
    }

    #pragma unroll 2
    for (int ks = 0; ks < 8; ++ks) {
        const size_t pan = (size_t)ks * 4 * 4096 * 8;
        half8 a[4], b[4];
        #pragma unroll
        for (int f = 0; f < 4; ++f) {
            a[f] = *(const half8*)(A + pan + ra0[f]);
            b[f] = *(const half8*)(B + pan + rb0[f]);
        }
        #pragma unroll
        for (int fm = 0; fm < 4; ++fm)
            #pragma unroll
            for (int fn = 0; fn < 4; ++fn)
                acc[fm][fn] = __builtin_amdgcn_mfma_f32_16x16x32_f16(
                    a[fm], b[fn], acc[fm][fn], 0, 0, 0);
    }

    // store: C/D layout col=lane&15, row=(lane>>4)*4+reg  (validated)
    #pragma unroll
    for (int fm = 0; fm < 4; ++fm)
        #pragma unroll
        for (int fn = 0; fn < 4; ++fn)
            #pragma unroll
            for (int r = 0; r < 4; ++r) {
                unsigned short o = f2bf_rne(acc[fm][fn][r]);
                Gb[(size_t)(s0 + wm + fm * 16 + fq * 4 + r) * SP + t0 + wn + fn * 16 + fr] = o;
            }
}

// ---------------------------------------------------------------------------
// Kernel 1-fallback (round-3..6 validated): LDS-staged bf16x3 GEMM (fp32 in)
// ---------------------------------------------------------------------------
__global__ __launch_bounds__(256, 2) void g_gemm(
    const float* __restrict__ contentb,
    const float* __restrict__ style,
    unsigned short* __restrict__ Gb)
{
    __shared__ __attribute__((aligned(16))) short Ah[4 * 128 * 8];
    __shared__ __attribute__((aligned(16))) short Al[4 * 128 * 8];
    __shared__ __attribute__((aligned(16))) short Bh[4 * 128 * 8];
    __shared__ __attribute__((aligned(16))) short Bl[4 * 128 * 8];

    const int tid  = threadIdx.x;
    const int s0   = blockIdx.x * 128;
    const int t0   = blockIdx.y * 128;
    const int wave = tid >> 6, lane = tid & 63;
    const int wm = (wave >> 1) * 64, wn = (wave & 1) * 64;
    const int fr = lane & 15;
    const int fq = lane >> 4;
    const int sm = tid & 127;
    const int sl = tid >> 7;

    float4v acc[4][4];
    #pragma unroll
    for (int i = 0; i < 4; ++i)
        #pragma unroll
        for (int j = 0; j < 4; ++j) acc[i][j] = (float4v)(0.f);

    for (int k0 = 0; k0 < 256; k0 += 32) {
        __syncthreads();
        #pragma unroll
        for (int h = 0; h < 2; ++h) {
            const float* src = h ? style : contentb;
            const int rb = h ? t0 : s0;
            short* dh = h ? Bh : Ah;
            short* dl = h ? Bl : Al;
            float v[16];
            #pragma unroll
            for (int j = 0; j < 16; ++j)
                v[j] = src[(size_t)(k0 + sl * 16 + j) * SP + rb + sm];
            short8 h0, h1, l0, l1;
            #pragma unroll
            for (int j = 0; j < 8; ++j) {
                unsigned ua = __float_as_uint(v[j]);
                unsigned ub = __float_as_uint(v[j + 8]);
                h0[j] = (short)(ua >> 16);
                h1[j] = (short)(ub >> 16);
                float ra  = v[j]     - __uint_as_float(ua & 0xffff0000u);
                float rb2 = v[j + 8] - __uint_as_float(ub & 0xffff0000u);
                l0[j] = (short)(__float_as_uint(ra) >> 16);
                l1[j] = (short)(__float_as_uint(rb2) >> 16);
            }
            *(short8*)(dh + ((sl * 2)     * 128 + sm) * 8) = h0;
            *(short8*)(dh + ((sl * 2 + 1) * 128 + sm) * 8) = h1;
            *(short8*)(dl + ((sl * 2)     * 128 + sm) * 8) = l0;
            *(short8*)(dl + ((sl * 2 + 1) * 128 + sm) * 8) = l1;
        }
        __syncthreads();

        short8 ah[4], al[4], bh[4], bl[4];
        #pragma unroll
        for (int f = 0; f < 4; ++f) {
            const int ra = (fq * 128 + wm + f * 16 + fr) * 8;
            const int rb = (fq * 128 + wn + f * 16 + fr) * 8;
            ah[f] = *(const short8*)(Ah + ra);
            al[f] = *(const short8*)(Al + ra);
            bh[f] = *(const short8*)(Bh + rb);
            bl[f] = *(const short8*)(Bl + rb);
        }
        #pragma unroll
        for (int fm = 0; fm < 4; ++fm)
            #pragma unroll
            for (int fn = 0; fn < 4; ++fn) {
                acc[fm][fn] = __builtin_amdgcn_mfma_f32_16x16x32_bf16(ah[fm], bh[fn], acc[fm][fn], 0, 0, 0);
                acc[fm][fn] = __builtin_amdgcn_mfma_f32_16x16x32_bf16(ah[fm], bl[fn], acc[fm][fn], 0, 0, 0);
                acc[fm][fn] = __builtin_amdgcn_mfma_f32_16x16x32_bf16(al[fm], bh[fn], acc[fm][fn], 0, 0, 0);
            }
    }

    #pragma unroll
    for (int fm = 0; fm < 4; ++fm)
        #pragma unroll
        for (int fn = 0; fn < 4; ++fn)
            #pragma unroll
            for (int r = 0; r < 4; ++r) {
                unsigned short o = f2bf_rne(acc[fm][fn][r]);
                Gb[(size_t)(s0 + wm + fm * 16 + fq * 4 + r) * SP + t0 + wn + fn * 16 + fr] = o;
            }
}

// ---------------------------------------------------------------------------
// Kernel 2 (REVERTED to round-5/6 validated): direct-G vectorized stencil +
// global per-q top-2. One wave per q; batched over blockIdx.y.
// ---------------------------------------------------------------------------
__global__ __launch_bounds__(256) void stencil_direct(
    const unsigned short* __restrict__ G0,
    const float* __restrict__ enc_bias,
    u64* __restrict__ cand2, int bbase)
{
    const int bl = blockIdx.y;
    const unsigned short* G = G0 + (size_t)bl * SPSP;
    const int b = bbase + bl;

    const int q = blockIdx.x * 4 + (threadIdx.x >> 6);
    const int lane = threadIdx.x & 63;
    const int y = q / ND, x = q - y * ND;
    const int jg = (lane & 7) * 8;
    const int ig = lane >> 3;
    const unsigned short* Gq = G + (size_t)(y * 64 + x) * SP;

    u64 k1 = 0, k2 = 0;
    for (int it = 0; it < 8; ++it) {
        const int i = it * 8 + ig;
        if (i <= 61) {
            float f[8];
            #pragma unroll
            for (int j = 0; j < 8; ++j) f[j] = 0.f;
            #pragma unroll
            for (int u = 0; u < 3; ++u) {
                #pragma unroll
                for (int v = 0; v < 3; ++v) {
                    const unsigned short* rp =
                        Gq + (size_t)(u * 64 + v) * SP + (i + u) * 64 + jg;
                    ushort8 a = *(const ushort8*)rp;
                    unsigned e = (jg < 56) ? *(const unsigned*)(rp + 8) : 0u;
                    float w8 = bf2f((unsigned short)(e & 0xffffu));
                    float w9 = bf2f((unsigned short)(e >> 16));
                    if (v == 0) {
                        #pragma unroll
                        for (int j = 0; j < 8; ++j) f[j] += bf2f(a[j]);
                    } else if (v == 1) {
                        #pragma unroll
                        for (int j = 0; j < 7; ++j) f[j] += bf2f(a[j + 1]);
                        f[7] += w8;
                    } else {
                        #pragma unroll
                        for (int j = 0; j < 6; ++j) f[j] += bf2f(a[j + 2]);
                        f[6] += w8;
                        f[7] += w9;
                    }
                }
            }
            #pragma unroll
            for (int j = 0; j < 8; ++j) {
                int jj = jg + j;
                if (jj <= 61) {
                    int p = i * ND + jj;
                    float fv = f[j] + enc_bias[p];
                    u64 key = ((u64)orderf(fv) << 32) | (unsigned)(NP - 1 - p);
                    if (key > k1) { k2 = k1; k1 = key; }
                    else if (key > k2) k2 = key;
                }
            }
        }
    }

    #pragma unroll
    for (int d = 1; d < 64; d <<= 1) {
        u64 o1 = __shfl_xor(k1, d, 64);
        u64 o2 = __shfl_xor(k2, d, 64);
        u64 hi = k1 > o1 ? k1 : o1;
        u64 lo = k1 > o1 ? o1 : k1;
        u64 m2 = k2 > o2 ? k2 : o2;
        k1 = hi;
        k2 = lo > m2 ? lo : m2;
    }
    if (lane == 0) {
        size_t o = (size_t)(b * NP + q) * 2;
        cand2[o] = k1;
        cand2[o + 1] = k2;
    }
}

// ---------------------------------------------------------------------------
// Kernel 3 (NEW): skip bound as round 7 (validated), but exact rescore reads
// content_t / style_t with float4-coalesced rows (64 lanes x 4 = 256 c).
// ---------------------------------------------------------------------------
__global__ __launch_bounds__(128) void rescore6(
    const float* __restrict__ content_t, // [4][4096][256]
    const float* __restrict__ style_t,   // [4096][256]
    const float* __restrict__ enc_bias,
    const unsigned short* __restrict__ G0,
    const float* __restrict__ na_c,      // [4][4096]
    const float* __restrict__ nb_s,      // [4096]
    const u64* __restrict__ cand2,
    int* __restrict__ idx, int bbase)
{
    __shared__ float sc[2];
    __shared__ int   pp[2];
    const int bl = blockIdx.x / NP;
    const int q  = blockIdx.x - bl * NP;
    const int b  = bbase + bl;
    const int qa = b * NP + q;
    const unsigned short* G = G0 + (size_t)bl * SPSP;
    const int tid = threadIdx.x;
    const int wave = tid >> 6, lane = tid & 63;
    const int y = q / ND, x = q - y * ND;

    const u64 k1 = cand2[(size_t)qa * 2];
    const u64 k2 = cand2[(size_t)qa * 2 + 1];
    const int p1 = NP - 1 - (int)(k1 & 0xffffffffu);
    const int p2 = NP - 1 - (int)(k2 & 0xffffffffu);
    const float f1 = unorderf((unsigned int)(k1 >> 32));
    const float f2 = unorderf((unsigned int)(k2 >> 32));

    if (k2 == 0ull) {
        if (tid == 0) idx[qa] = p1;
        return;
    }

    // per-candidate screening bound (round-7 validated)
    float eul = 0.f;
    {
        const int side = lane >> 4;            // lanes 0-8 -> p1, 16-24 -> p2
        const int d = lane & 15;
        if (side < 2 && d < 9) {
            int u = d / 3, v = d - u * 3;
            int pc = side ? p2 : p1;
            int pi = pc / ND, pj = pc - pi * ND;
            int sd = (y + u) * 64 + (x + v);
            int td = (pi + u) * 64 + (pj + v);
            unsigned short g = G[(size_t)sd * SP + td];
            float gf = bf2f(g);
            float hulp = __uint_as_float(__float_as_uint(gf) & 0x7f800000u) * HULP;
            eul = hulp + SPLIT_REL * na_c[b * SP + sd] * nb_s[td];
        }
    }
    #pragma unroll
    for (int d = 1; d < 64; d <<= 1) eul += __shfl_xor(eul, d, 64);

    if ((f1 - f2) > eul + EPS_G) {
        if (tid == 0) idx[qa] = p1;
        return;
    }

    // exact fp32 dot, fully coalesced: lane covers c = lane*4 .. lane*4+3
    const int pc = wave ? p2 : p1;
    const int pi = pc / ND, pj = pc - pi * ND;
    const float* ctb = content_t + (size_t)b * NCSP;
    float s = 0.f;
    #pragma unroll
    for (int u = 0; u < 3; ++u) {
        #pragma unroll
        for (int v = 0; v < 3; ++v) {
            const float* cw = ctb + (size_t)((y + u) * 64 + x + v) * 256 + lane * 4;
            const float* sw = style_t + (size_t)((pi + u) * 64 + pj + v) * 256 + lane * 4;
            float4v c4 = *(const float4v*)cw;
            float4v s4 = *(const float4v*)sw;
            s = fmaf(c4[0], s4[0], s);
            s = fmaf(c4[1], s4[1], s);
            s = fmaf(c4[2], s4[2], s);
            s = fmaf(c4[3], s4[3], s);
        }
    }
    #pragma unroll
    for (int d = 32; d; d >>= 1) s += __shfl_xor(s, d, 64);
    if (lane == 0) { sc[wave] = s + enc_bias[pc]; pp[wave] = pc; }
    __syncthreads();
    if (tid == 0) {
        float s0 = sc[0], s1 = sc[1];
        int q0 = pp[0], q1 = pp[1];
        idx[qa] = (s1 > s0 || (s1 == s0 && q1 < q0)) ? q1 : q0;
    }
}

// ---------------------------------------------------------------------------
// Kernel 4: output via style_t with LDS row accumulation (validated)
// ---------------------------------------------------------------------------
__global__ __launch_bounds__(256) void produce_out2(
    const float* __restrict__ style_t,
    const float* __restrict__ dec_bias,
    const float* __restrict__ intra_bias,
    const int* __restrict__ idx,
    float* __restrict__ out)
{
    __shared__ float orow[64][129];
    __shared__ int pidx[3][ND];

    const int bh = blockIdx.x;
    const int b = bh >> 6, h = bh & 63;
    const int ch = blockIdx.y;
    const int tid = threadIdx.x;

    if (tid < 3 * ND) {
        int u = tid / ND, xx = tid - u * ND;
        int yy = h - u;
        pidx[u][xx] = (yy >= 0 && yy < ND) ? idx[b * NP + yy * ND + xx] : 0;
    }
    for (int i = tid; i < 64 * 129; i += 256) ((float*)orow)[i] = 0.f;
    __syncthreads();

    const int cl = tid & 127;
    const int xo = tid >> 7;
    for (int u = 0; u < 3; ++u) {
        int yy = h - u;
        if (yy < 0 || yy >= ND) continue;
        #pragma unroll
        for (int v = 0; v < 3; ++v) {
            for (int xi = (xo + v) & 1; xi < ND; xi += 2) {
                int p = pidx[u][xi];
                int pi = p / ND, pj = p - pi * ND;
                float sv = style_t[(size_t)(pi * 64 + pj + u * 64 + v) * 256 + ch * 128 + cl];
                orow[xi + v][cl] += sv;
            }
        }
    }
    __syncthreads();

    const int w = tid & 63, cg = tid >> 6;
    const int cu  = (h < 2 ? h : 2) - (h > 61 ? h - 61 : 0) + 1;
    const int cvw = (w < 2 ? w : 2) - (w > 61 ? w - 61 : 0) + 1;
    const float cnt = (float)(cu * cvw);
    #pragma unroll 4
    for (int ci = 0; ci < 32; ++ci) {
        int cll = cg * 32 + ci;
        int c = ch * 128 + cll;
        float val = (orow[w][cll] + dec_bias[c]) / (cnt + intra_bias[c]);
        out[(((size_t)b * NC + c) * 64 + h) * 64 + w] = val;
    }
}

// ---------------------------------------------------------------------------
extern "C" void kernel_launch(void* const* d_in, const int* in_sizes, int n_in,
                              void* d_out, int out_size, void* d_ws, size_t ws_size,
                              hipStream_t stream) {
    const float* content    = (const float*)d_in[0];
    const float* style      = (const float*)d_in[1];
    const float* enc_bias   = (const float*)d_in[2];
    const float* dec_bias   = (const float*)d_in[3];
    const float* intra_bias = (const float*)d_in[4];
    float* out = (float*)d_out;

    const size_t G_BYTES     = SPSP * 2;                   //  33,554,432
    const size_t CAND2_BYTES = (size_t)4 * NP * 2 * 8;     //     246,016
    const size_t IDX_BYTES   = (size_t)4 * NP * 4;         //      61,504
    const size_t ST_BYTES    = NCSP * 4;                   //   4,194,304
    const size_t CT_BYTES    = (size_t)4 * NCSP * 4;       //  16,777,216
    const size_t P16_BYTES   = NCSP * 2;                   //   2,097,152
    const size_t NA_BYTES    = (size_t)4 * SP * 4;         //      65,536
    const size_t NB_BYTES    = (size_t)SP * 4;             //      16,384

    // Tier A: 4 G's resident + fp16 panels + transposes + norms  (~165 MB)
    const size_t A_OFF_CAND2 = 4 * G_BYTES;
    const size_t A_OFF_IDX   = A_OFF_CAND2 + CAND2_BYTES;
    const size_t A_OFF_ST    = A_OFF_IDX + IDX_BYTES;
    const size_t A_OFF_CT    = A_OFF_ST + ST_BYTES;
    const size_t A_OFF_PS    = A_OFF_CT + CT_BYTES;
    const size_t A_OFF_PC    = A_OFF_PS + P16_BYTES;
    const size_t A_OFF_NA    = A_OFF_PC + 4 * P16_BYTES;
    const size_t A_OFF_NB    = A_OFF_NA + NA_BYTES;
    const size_t NEED_A      = A_OFF_NB + NB_BYTES;

    // Tier B: single G + bf16x3 fp32-input GEMM per batch (~54.6 MB)
    const size_t B_OFF_CAND2 = G_BYTES;
    const size_t B_OFF_IDX   = B_OFF_CAND2 + CAND2_BYTES;
    const size_t B_OFF_ST    = B_OFF_IDX + IDX_BYTES;
    const size_t B_OFF_CT    = B_OFF_ST + ST_BYTES;
    const size_t B_OFF_NA    = B_OFF_CT + CT_BYTES;
    const size_t B_OFF_NB    = B_OFF_NA + NA_BYTES;
    const size_t NEED_B      = B_OFF_NB + NB_BYTES;
    (void)NEED_B;

    if (ws_size >= NEED_A) {
        unsigned short* G4 = (unsigned short*)d_ws;
        u64* cand2      = (u64*)((char*)d_ws + A_OFF_CAND2);
        int* idx        = (int*)((char*)d_ws + A_OFF_IDX);
        float* style_t  = (float*)((char*)d_ws + A_OFF_ST);
        float* content_t = (float*)((char*)d_ws + A_OFF_CT);
        unsigned short* PS = (unsigned short*)((char*)d_ws + A_OFF_PS);
        unsigned short* PC = (unsigned short*)((char*)d_ws + A_OFF_PC);
        float* na_c     = (float*)((char*)d_ws + A_OFF_NA);
        float* nb_s     = (float*)((char*)d_ws + A_OFF_NB);

        transpose_b<<<dim3(128, 8, 1), 256, 0, stream>>>(style, style_t);
        transpose_b<<<dim3(128, 8, 4), 256, 0, stream>>>(content, content_t);
        col_norms<<<dim3(80), 256, 0, stream>>>(content, style, na_c, nb_s);
        panels_f16<<<dim3(32, 8, 1), 256, 0, stream>>>(style, PS);
        panels_f16<<<dim3(32, 8, 4), 256, 0, stream>>>(content, PC);
        g_gemm_f16<<<dim3(32, 32, 4), 256, 0, stream>>>(PC, PS, G4);
        stencil_direct<<<dim3(NP / 4, 4), 256, 0, stream>>>(G4, enc_bias, cand2, 0);
        rescore6<<<dim3(4 * NP), 128, 0, stream>>>(
            content_t, style_t, enc_bias, G4, na_c, nb_s, cand2, idx, 0);
        produce_out2<<<dim3(4 * 64, 2), 256, 0, stream>>>(
            style_t, dec_bias, intra_bias, idx, out);
    } else {
        unsigned short* Gb = (unsigned short*)d_ws;
        u64* cand2      = (u64*)((char*)d_ws + B_OFF_CAND2);
        int* idx        = (int*)((char*)d_ws + B_OFF_IDX);
        float* style_t  = (float*)((char*)d_ws + B_OFF_ST);
        float* content_t = (float*)((char*)d_ws + B_OFF_CT);
        float* na_c     = (float*)((char*)d_ws + B_OFF_NA);
        float* nb_s     = (float*)((char*)d_ws + B_OFF_NB);

        transpose_b<<<dim3(128, 8, 1), 256, 0, stream>>>(style, style_t);
        transpose_b<<<dim3(128, 8, 4), 256, 0, stream>>>(content, content_t);
        col_norms<<<dim3(80), 256, 0, stream>>>(content, style, na_c, nb_s);
        for (int b = 0; b < 4; ++b) {
            g_gemm<<<dim3(32, 32), 256, 0, stream>>>(
                content + (size_t)b * NCSP, style, Gb);
            stencil_direct<<<dim3(NP / 4, 1), 256, 0, stream>>>(Gb, enc_bias, cand2, b);
            rescore6<<<dim3(NP), 128, 0, stream>>>(
                content_t, style_t, enc_bias, Gb, na_c, nb_s, cand2, idx, b);
        }
        produce_out2<<<dim3(4 * 64, 2), 256, 0, stream>>>(
            style_t, dec_bias, intra_bias, idx, out);
    }
}

// Round 9
// 307.119 us; speedup vs baseline: 1.2800x; 1.0402x over previous
//
#include <hip/hip_runtime.h>
#include <stdint.h>

// Problem constants (B=4, C=256, H=W=64, PATCH=3, STRIDE=1)
#define NP   3844   // 62*62 patches == per-batch feat pixels
#define ND   62
#define NC   256
#define HW   64
#define SP   4096   // 64*64 pixels per image
#define SPSP ((size_t)SP * SP)      // G elements per batch
#define NCSP ((size_t)NC * SP)      // panel elements per batch
#define EPS_G 0.15f        // margin: MFMA fp32 accum + stencil adds + subnormals
#define HULP 0.00390625f   // half-ulp factor for bf16 store (2^-8)
#define SPLIT_REL 0.0009765625f  // 2^-10: fp16 quantization of both operands

typedef __attribute__((ext_vector_type(8))) short short8;
typedef __attribute__((ext_vector_type(8))) unsigned short ushort8;
typedef __attribute__((ext_vector_type(8))) _Float16 half8;
typedef __attribute__((ext_vector_type(4))) float float4v;
typedef __attribute__((ext_vector_type(2))) float float2v;
typedef unsigned long long u64;

__device__ __forceinline__ unsigned int orderf(float v) {
    unsigned int u = __float_as_uint(v);
    return (u & 0x80000000u) ? ~u : (u | 0x80000000u);
}
__device__ __forceinline__ float unorderf(unsigned int k) {
    return __uint_as_float((k & 0x80000000u) ? (k ^ 0x80000000u) : ~k);
}
__device__ __forceinline__ float bf2f(unsigned short h) {
    return __uint_as_float(((unsigned int)h) << 16);
}
__device__ __forceinline__ unsigned short f2bf_rne(float a) {
    unsigned ua = __float_as_uint(a);
    return (unsigned short)((ua + 0x7fffu + ((ua >> 16) & 1u)) >> 16);
}

// ---------------------------------------------------------------------------
// Kernel 0: batched [256][4096] -> [4096][256] fp32 transpose (validated)
// ---------------------------------------------------------------------------
__global__ __launch_bounds__(256) void transpose_b(
    const float* __restrict__ src0, float* __restrict__ dst0)
{
    const float* src = src0 + (size_t)blockIdx.z * NCSP;
    float* dst = dst0 + (size_t)blockIdx.z * NCSP;
    __shared__ float t[32][33];
    const int s0 = blockIdx.x * 32;
    const int c0 = blockIdx.y * 32;
    const int col = threadIdx.x & 31, r8 = threadIdx.x >> 5;
    #pragma unroll
    for (int i = 0; i < 4; ++i) {
        int r = r8 + i * 8;
        t[r][col] = src[(size_t)(c0 + r) * SP + s0 + col];
    }
    __syncthreads();
    #pragma unroll
    for (int i = 0; i < 4; ++i) {
        int r = r8 + i * 8;
        dst[(size_t)(s0 + r) * 256 + c0 + col] = t[col][r];
    }
}

// ---------------------------------------------------------------------------
// Kernel 0b: column L2 norms over c (validated)
// ---------------------------------------------------------------------------
__global__ __launch_bounds__(256) void col_norms(
    const float* __restrict__ content, const float* __restrict__ style,
    float* __restrict__ na_c, float* __restrict__ nb_s)
{
    const int blk = blockIdx.x, tid = threadIdx.x;
    const float* src;
    float* dst;
    int s;
    if (blk < 64) {
        int b = blk >> 4, ch = blk & 15;
        src = content + (size_t)b * NCSP;
        dst = na_c + b * SP;
        s = ch * 256 + tid;
    } else {
        src = style;
        dst = nb_s;
        s = (blk - 64) * 256 + tid;
    }
    float sum = 0.f;
    #pragma unroll 4
    for (int c = 0; c < NC; ++c) {
        float v = src[(size_t)c * SP + s];
        sum = fmaf(v, v, sum);
    }
    dst[s] = sqrtf(sum);
}

// ---------------------------------------------------------------------------
// Kernel 0c: fp32 -> fp16 (RNE) k-panel layout, batched over z (validated)
// ---------------------------------------------------------------------------
__global__ __launch_bounds__(256) void panels_f16(
    const float* __restrict__ src0, unsigned short* __restrict__ P0)
{
    const float* src = src0 + (size_t)blockIdx.z * NCSP;
    unsigned short* P = P0 + (size_t)blockIdx.z * NCSP;

    __shared__ unsigned short buf[512 * 8];
    const int kp = blockIdx.x;            // 0..31
    const int s0 = blockIdx.y * 512;      // 0..7
    const int tid = threadIdx.x;
    #pragma unroll
    for (int kk = 0; kk < 8; ++kk) {
        #pragma unroll
        for (int h = 0; h < 2; ++h) {
            int s = tid + h * 256;
            float a = src[(size_t)(kp * 8 + kk) * SP + s0 + s];
            _Float16 hf = (_Float16)a;    // RNE
            unsigned short hb;
            __builtin_memcpy(&hb, &hf, 2);
            buf[s * 8 + kk] = hb;
        }
    }
    __syncthreads();
    #pragma unroll
    for (int h = 0; h < 2; ++h) {
        int s = tid + h * 256;
        size_t o = ((size_t)kp * 4096 + s0 + s) * 8;
        *(ushort8*)(P + o) = *(const ushort8*)(buf + s * 8);
    }
}

// ---------------------------------------------------------------------------
// Kernel 1: fp16 single-MFMA panel GEMM (validated)
// ---------------------------------------------------------------------------
__global__ __launch_bounds__(256) void g_gemm_f16(
    const unsigned short* __restrict__ A0,
    const unsigned short* __restrict__ B,
    unsigned short* __restrict__ G0)
{
    const unsigned short* A = A0 + (size_t)blockIdx.z * NCSP;
    unsigned short* Gb = G0 + (size_t)blockIdx.z * SPSP;

    const int tid  = threadIdx.x;
    const int s0   = blockIdx.x * 128;
    const int t0   = blockIdx.y * 128;
    const int wave = tid >> 6, lane = tid & 63;
    const int wm = (wave >> 1) * 64, wn = (wave & 1) * 64;
    const int fr = lane & 15;
    const int fq = lane >> 4;     // k-quad -> panel offset

    float4v acc[4][4];
    #pragma unroll
    for (int i = 0; i < 4; ++i)
        #pragma unroll
        for (int j = 0; j < 4; ++j) acc[i][j] = (float4v)(0.f);

    size_t ra0[4], rb0[4];
    #pragma unroll
    for (int f = 0; f < 4; ++f) {
        ra0[f] = ((size_t)fq * 4096 + s0 + wm + f * 16 + fr) * 8;
        rb0[f] = ((size_t)fq * 4096 + t0 + wn + f * 16 + fr) * 8;
    }

    #pragma unroll 2
    for (int ks = 0; ks < 8; ++ks) {
        const size_t pan = (size_t)ks * 4 * 4096 * 8;
        half8 a[4], b[4];
        #pragma unroll
        for (int f = 0; f < 4; ++f) {
            a[f] = *(const half8*)(A + pan + ra0[f]);
            b[f] = *(const half8*)(B + pan + rb0[f]);
        }
        #pragma unroll
        for (int fm = 0; fm < 4; ++fm)
            #pragma unroll
            for (int fn = 0; fn < 4; ++fn)
                acc[fm][fn] = __builtin_amdgcn_mfma_f32_16x16x32_f16(
                    a[fm], b[fn], acc[fm][fn], 0, 0, 0);
    }

    #pragma unroll
    for (int fm = 0; fm < 4; ++fm)
        #pragma unroll
        for (int fn = 0; fn < 4; ++fn)
            #pragma unroll
            for (int r = 0; r < 4; ++r) {
                unsigned short o = f2bf_rne(acc[fm][fn][r]);
                Gb[(size_t)(s0 + wm + fm * 16 + fq * 4 + r) * SP + t0 + wn + fn * 16 + fr] = o;
            }
}

// ---------------------------------------------------------------------------
// Kernel 1-fallback (validated): LDS-staged bf16x3 GEMM (fp32 in)
// ---------------------------------------------------------------------------
__global__ __launch_bounds__(256, 2) void g_gemm(
    const float* __restrict__ contentb,
    const float* __restrict__ style,
    unsigned short* __restrict__ Gb)
{
    __shared__ __attribute__((aligned(16))) short Ah[4 * 128 * 8];
    __shared__ __attribute__((aligned(16))) short Al[4 * 128 * 8];
    __shared__ __attribute__((aligned(16))) short Bh[4 * 128 * 8];
    __shared__ __attribute__((aligned(16))) short Bl[4 * 128 * 8];

    const int tid  = threadIdx.x;
    const int s0   = blockIdx.x * 128;
    const int t0   = blockIdx.y * 128;
    const int wave = tid >> 6, lane = tid & 63;
    const int wm = (wave >> 1) * 64, wn = (wave & 1) * 64;
    const int fr = lane & 15;
    const int fq = lane >> 4;
    const int sm = tid & 127;
    const int sl = tid >> 7;

    float4v acc[4][4];
    #pragma unroll
    for (int i = 0; i < 4; ++i)
        #pragma unroll
        for (int j = 0; j < 4; ++j) acc[i][j] = (float4v)(0.f);

    for (int k0 = 0; k0 < 256; k0 += 32) {
        __syncthreads();
        #pragma unroll
        for (int h = 0; h < 2; ++h) {
            const float* src = h ? style : contentb;
            const int rb = h ? t0 : s0;
            short* dh = h ? Bh : Ah;
            short* dl = h ? Bl : Al;
            float v[16];
            #pragma unroll
            for (int j = 0; j < 16; ++j)
                v[j] = src[(size_t)(k0 + sl * 16 + j) * SP + rb + sm];
            short8 h0, h1, l0, l1;
            #pragma unroll
            for (int j = 0; j < 8; ++j) {
                unsigned ua = __float_as_uint(v[j]);
                unsigned ub = __float_as_uint(v[j + 8]);
                h0[j] = (short)(ua >> 16);
                h1[j] = (short)(ub >> 16);
                float ra  = v[j]     - __uint_as_float(ua & 0xffff0000u);
                float rb2 = v[j + 8] - __uint_as_float(ub & 0xffff0000u);
                l0[j] = (short)(__float_as_uint(ra) >> 16);
                l1[j] = (short)(__float_as_uint(rb2) >> 16);
            }
            *(short8*)(dh + ((sl * 2)     * 128 + sm) * 8) = h0;
            *(short8*)(dh + ((sl * 2 + 1) * 128 + sm) * 8) = h1;
            *(short8*)(dl + ((sl * 2)     * 128 + sm) * 8) = l0;
            *(short8*)(dl + ((sl * 2 + 1) * 128 + sm) * 8) = l1;
        }
        __syncthreads();

        short8 ah[4], al[4], bh[4], bl[4];
        #pragma unroll
        for (int f = 0; f < 4; ++f) {
            const int ra = (fq * 128 + wm + f * 16 + fr) * 8;
            const int rb = (fq * 128 + wn + f * 16 + fr) * 8;
            ah[f] = *(const short8*)(Ah + ra);
            al[f] = *(const short8*)(Al + ra);
            bh[f] = *(const short8*)(Bh + rb);
            bl[f] = *(const short8*)(Bl + rb);
        }
        #pragma unroll
        for (int fm = 0; fm < 4; ++fm)
            #pragma unroll
            for (int fn = 0; fn < 4; ++fn) {
                acc[fm][fn] = __builtin_amdgcn_mfma_f32_16x16x32_bf16(ah[fm], bh[fn], acc[fm][fn], 0, 0, 0);
                acc[fm][fn] = __builtin_amdgcn_mfma_f32_16x16x32_bf16(ah[fm], bl[fn], acc[fm][fn], 0, 0, 0);
                acc[fm][fn] = __builtin_amdgcn_mfma_f32_16x16x32_bf16(al[fm], bh[fn], acc[fm][fn], 0, 0, 0);
            }
    }

    #pragma unroll
    for (int fm = 0; fm < 4; ++fm)
        #pragma unroll
        for (int fn = 0; fn < 4; ++fn)
            #pragma unroll
            for (int r = 0; r < 4; ++r) {
                unsigned short o = f2bf_rne(acc[fm][fn][r]);
                Gb[(size_t)(s0 + wm + fm * 16 + fq * 4 + r) * SP + t0 + wn + fn * 16 + fr] = o;
            }
}

// ---------------------------------------------------------------------------
// Kernel 2 (NEW): stencil with ILP-restructured top-2.
// Same addressing/extraction as validated stencil_direct, but:
//  - all 9 windows loaded up front per iteration (latency overlap)
//  - 4 independent float/int top-2 accumulators (slot = j>>1) break the
//    64-long serial u64 chain; keys built only for the 8 finalists
//  - enc_bias via aligned float2 loads (8B alignment guaranteed; jg=56 guarded)
// ---------------------------------------------------------------------------
__global__ __launch_bounds__(256) void stencil_ilp(
    const unsigned short* __restrict__ G0,
    const float* __restrict__ enc_bias,
    u64* __restrict__ cand2, int bbase)
{
    const int bl = blockIdx.y;
    const unsigned short* G = G0 + (size_t)bl * SPSP;
    const int b = bbase + bl;

    const int q = blockIdx.x * 4 + (threadIdx.x >> 6);
    const int lane = threadIdx.x & 63;
    const int y = q / ND, x = q - y * ND;
    const int jg = (lane & 7) * 8;
    const int ig = lane >> 3;
    const unsigned short* Gq = G + (size_t)(y * 64 + x) * SP;

    float fb1[4], fb2[4];
    int   ib1[4], ib2[4];
    #pragma unroll
    for (int s = 0; s < 4; ++s) {
        fb1[s] = -3.0e38f; fb2[s] = -3.0e38f; ib1[s] = 0; ib2[s] = 0;
    }

    for (int it = 0; it < 8; ++it) {
        const int i = it * 8 + ig;
        if (i <= 61) {
            // --- load all 9 windows (independent; overlapped latency) ---
            ushort8 w[9]; unsigned e[9];
            #pragma unroll
            for (int u = 0; u < 3; ++u)
                #pragma unroll
                for (int v = 0; v < 3; ++v) {
                    const unsigned short* rp =
                        Gq + (size_t)(u * 64 + v) * SP + (i + u) * 64 + jg;
                    w[u * 3 + v] = *(const ushort8*)rp;
                    e[u * 3 + v] = (jg < 56) ? *(const unsigned*)(rp + 8) : 0u;
                }
            // --- enc bias: 8B-aligned float2 loads ((i*62+jg) even) ---
            const float* ep = enc_bias + i * ND + jg;
            float eb[8];
            {
                float2v a0 = *(const float2v*)(ep);
                float2v a1 = *(const float2v*)(ep + 2);
                float2v a2 = *(const float2v*)(ep + 4);
                eb[0] = a0[0]; eb[1] = a0[1];
                eb[2] = a1[0]; eb[3] = a1[1];
                eb[4] = a2[0]; eb[5] = a2[1];
                if (jg < 56) {
                    float2v a3 = *(const float2v*)(ep + 6);
                    eb[6] = a3[0]; eb[7] = a3[1];
                } else { eb[6] = 0.f; eb[7] = 0.f; }   // jj=62,63 masked anyway
            }
            // --- 9-point diagonal sum (validated extraction) ---
            float f[8];
            #pragma unroll
            for (int j = 0; j < 8; ++j) f[j] = 0.f;
            #pragma unroll
            for (int u = 0; u < 3; ++u) {
                #pragma unroll
                for (int v = 0; v < 3; ++v) {
                    const int dd = u * 3 + v;
                    float w8 = bf2f((unsigned short)(e[dd] & 0xffffu));
                    float w9 = bf2f((unsigned short)(e[dd] >> 16));
                    if (v == 0) {
                        #pragma unroll
                        for (int j = 0; j < 8; ++j) f[j] += bf2f(w[dd][j]);
                    } else if (v == 1) {
                        #pragma unroll
                        for (int j = 0; j < 7; ++j) f[j] += bf2f(w[dd][j + 1]);
                        f[7] += w8;
                    } else {
                        #pragma unroll
                        for (int j = 0; j < 6; ++j) f[j] += bf2f(w[dd][j + 2]);
                        f[6] += w8;
                        f[7] += w9;
                    }
                }
            }
            // --- tournament into 4 independent slots ---
            const int pq = i * ND + jg;
            #pragma unroll
            for (int j = 0; j < 8; ++j) {
                int jj = jg + j;
                if (jj <= 61) {            // only jg=56, j>=6 masked
                    float fv = f[j] + eb[j];
                    int p = pq + j;
                    const int s = j >> 1;
                    bool gt1 = fv > fb1[s];
                    bool gt2 = fv > fb2[s];
                    fb2[s] = gt1 ? fb1[s] : (gt2 ? fv : fb2[s]);
                    ib2[s] = gt1 ? ib1[s] : (gt2 ? p  : ib2[s]);
                    fb1[s] = gt1 ? fv : fb1[s];
                    ib1[s] = gt1 ? p  : ib1[s];
                }
            }
        }
    }

    // --- per-lane merge: build 8 finalist keys, serial top-2 (validated) ---
    u64 k1 = 0, k2 = 0;
    #pragma unroll
    for (int s = 0; s < 4; ++s) {
        u64 ka = ((u64)orderf(fb1[s]) << 32) | (unsigned)(NP - 1 - ib1[s]);
        u64 kb = ((u64)orderf(fb2[s]) << 32) | (unsigned)(NP - 1 - ib2[s]);
        if (ka > k1) { k2 = k1; k1 = ka; } else if (ka > k2) k2 = ka;
        if (kb > k1) { k2 = k1; k1 = kb; } else if (kb > k2) k2 = kb;
    }

    // --- 64-lane butterfly (validated) ---
    #pragma unroll
    for (int d = 1; d < 64; d <<= 1) {
        u64 o1 = __shfl_xor(k1, d, 64);
        u64 o2 = __shfl_xor(k2, d, 64);
        u64 hi = k1 > o1 ? k1 : o1;
        u64 lo = k1 > o1 ? o1 : k1;
        u64 m2 = k2 > o2 ? k2 : o2;
        k1 = hi;
        k2 = lo > m2 ? lo : m2;
    }
    if (lane == 0) {
        size_t o = (size_t)(b * NP + q) * 2;
        cand2[o] = k1;
        cand2[o + 1] = k2;
    }
}

// ---------------------------------------------------------------------------
// Kernel 3 (validated round 8): norm-bound gap-skip + coalesced exact rescore
// ---------------------------------------------------------------------------
__global__ __launch_bounds__(128) void rescore6(
    const float* __restrict__ content_t, // [4][4096][256]
    const float* __restrict__ style_t,   // [4096][256]
    const float* __restrict__ enc_bias,
    const unsigned short* __restrict__ G0,
    const float* __restrict__ na_c,      // [4][4096]
    const float* __restrict__ nb_s,      // [4096]
    const u64* __restrict__ cand2,
    int* __restrict__ idx, int bbase)
{
    __shared__ float sc[2];
    __shared__ int   pp[2];
    const int bl = blockIdx.x / NP;
    const int q  = blockIdx.x - bl * NP;
    const int b  = bbase + bl;
    const int qa = b * NP + q;
    const unsigned short* G = G0 + (size_t)bl * SPSP;
    const int tid = threadIdx.x;
    const int wave = tid >> 6, lane = tid & 63;
    const int y = q / ND, x = q - y * ND;

    const u64 k1 = cand2[(size_t)qa * 2];
    const u64 k2 = cand2[(size_t)qa * 2 + 1];
    const int p1 = NP - 1 - (int)(k1 & 0xffffffffu);
    const int p2 = NP - 1 - (int)(k2 & 0xffffffffu);
    const float f1 = unorderf((unsigned int)(k1 >> 32));
    const float f2 = unorderf((unsigned int)(k2 >> 32));

    if (k2 == 0ull) {
        if (tid == 0) idx[qa] = p1;
        return;
    }

    float eul = 0.f;
    {
        const int side = lane >> 4;            // lanes 0-8 -> p1, 16-24 -> p2
        const int d = lane & 15;
        if (side < 2 && d < 9) {
            int u = d / 3, v = d - u * 3;
            int pc = side ? p2 : p1;
            int pi = pc / ND, pj = pc - pi * ND;
            int sd = (y + u) * 64 + (x + v);
            int td = (pi + u) * 64 + (pj + v);
            unsigned short g = G[(size_t)sd * SP + td];
            float gf = bf2f(g);
            float hulp = __uint_as_float(__float_as_uint(gf) & 0x7f800000u) * HULP;
            eul = hulp + SPLIT_REL * na_c[b * SP + sd] * nb_s[td];
        }
    }
    #pragma unroll
    for (int d = 1; d < 64; d <<= 1) eul += __shfl_xor(eul, d, 64);

    if ((f1 - f2) > eul + EPS_G) {
        if (tid == 0) idx[qa] = p1;
        return;
    }

    const int pc = wave ? p2 : p1;
    const int pi = pc / ND, pj = pc - pi * ND;
    const float* ctb = content_t + (size_t)b * NCSP;
    float s = 0.f;
    #pragma unroll
    for (int u = 0; u < 3; ++u) {
        #pragma unroll
        for (int v = 0; v < 3; ++v) {
            const float* cw = ctb + (size_t)((y + u) * 64 + x + v) * 256 + lane * 4;
            const float* sw = style_t + (size_t)((pi + u) * 64 + pj + v) * 256 + lane * 4;
            float4v c4 = *(const float4v*)cw;
            float4v s4 = *(const float4v*)sw;
            s = fmaf(c4[0], s4[0], s);
            s = fmaf(c4[1], s4[1], s);
            s = fmaf(c4[2], s4[2], s);
            s = fmaf(c4[3], s4[3], s);
        }
    }
    #pragma unroll
    for (int d = 32; d; d >>= 1) s += __shfl_xor(s, d, 64);
    if (lane == 0) { sc[wave] = s + enc_bias[pc]; pp[wave] = pc; }
    __syncthreads();
    if (tid == 0) {
        float s0 = sc[0], s1 = sc[1];
        int q0 = pp[0], q1 = pp[1];
        idx[qa] = (s1 > s0 || (s1 == s0 && q1 < q0)) ? q1 : q0;
    }
}

// ---------------------------------------------------------------------------
// Kernel 4: output via style_t with LDS row accumulation (validated)
// ---------------------------------------------------------------------------
__global__ __launch_bounds__(256) void produce_out2(
    const float* __restrict__ style_t,
    const float* __restrict__ dec_bias,
    const float* __restrict__ intra_bias,
    const int* __restrict__ idx,
    float* __restrict__ out)
{
    __shared__ float orow[64][129];
    __shared__ int pidx[3][ND];

    const int bh = blockIdx.x;
    const int b = bh >> 6, h = bh & 63;
    const int ch = blockIdx.y;
    const int tid = threadIdx.x;

    if (tid < 3 * ND) {
        int u = tid / ND, xx = tid - u * ND;
        int yy = h - u;
        pidx[u][xx] = (yy >= 0 && yy < ND) ? idx[b * NP + yy * ND + xx] : 0;
    }
    for (int i = tid; i < 64 * 129; i += 256) ((float*)orow)[i] = 0.f;
    __syncthreads();

    const int cl = tid & 127;
    const int xo = tid >> 7;
    for (int u = 0; u < 3; ++u) {
        int yy = h - u;
        if (yy < 0 || yy >= ND) continue;
        #pragma unroll
        for (int v = 0; v < 3; ++v) {
            for (int xi = (xo + v) & 1; xi < ND; xi += 2) {
                int p = pidx[u][xi];
                int pi = p / ND, pj = p - pi * ND;
                float sv = style_t[(size_t)(pi * 64 + pj + u * 64 + v) * 256 + ch * 128 + cl];
                orow[xi + v][cl] += sv;
            }
        }
    }
    __syncthreads();

    const int w = tid & 63, cg = tid >> 6;
    const int cu  = (h < 2 ? h : 2) - (h > 61 ? h - 61 : 0) + 1;
    const int cvw = (w < 2 ? w : 2) - (w > 61 ? w - 61 : 0) + 1;
    const float cnt = (float)(cu * cvw);
    #pragma unroll 4
    for (int ci = 0; ci < 32; ++ci) {
        int cll = cg * 32 + ci;
        int c = ch * 128 + cll;
        float val = (orow[w][cll] + dec_bias[c]) / (cnt + intra_bias[c]);
        out[(((size_t)b * NC + c) * 64 + h) * 64 + w] = val;
    }
}

// ---------------------------------------------------------------------------
extern "C" void kernel_launch(void* const* d_in, const int* in_sizes, int n_in,
                              void* d_out, int out_size, void* d_ws, size_t ws_size,
                              hipStream_t stream) {
    const float* content    = (const float*)d_in[0];
    const float* style      = (const float*)d_in[1];
    const float* enc_bias   = (const float*)d_in[2];
    const float* dec_bias   = (const float*)d_in[3];
    const float* intra_bias = (const float*)d_in[4];
    float* out = (float*)d_out;

    const size_t G_BYTES     = SPSP * 2;                   //  33,554,432
    const size_t CAND2_BYTES = (size_t)4 * NP * 2 * 8;     //     246,016
    const size_t IDX_BYTES   = (size_t)4 * NP * 4;         //      61,504
    const size_t ST_BYTES    = NCSP * 4;                   //   4,194,304
    const size_t CT_BYTES    = (size_t)4 * NCSP * 4;       //  16,777,216
    const size_t P16_BYTES   = NCSP * 2;                   //   2,097,152
    const size_t NA_BYTES    = (size_t)4 * SP * 4;         //      65,536
    const size_t NB_BYTES    = (size_t)SP * 4;             //      16,384

    // Tier A: 4 G's resident + fp16 panels + transposes + norms  (~165 MB)
    const size_t A_OFF_CAND2 = 4 * G_BYTES;
    const size_t A_OFF_IDX   = A_OFF_CAND2 + CAND2_BYTES;
    const size_t A_OFF_ST    = A_OFF_IDX + IDX_BYTES;
    const size_t A_OFF_CT    = A_OFF_ST + ST_BYTES;
    const size_t A_OFF_PS    = A_OFF_CT + CT_BYTES;
    const size_t A_OFF_PC    = A_OFF_PS + P16_BYTES;
    const size_t A_OFF_NA    = A_OFF_PC + 4 * P16_BYTES;
    const size_t A_OFF_NB    = A_OFF_NA + NA_BYTES;
    const size_t NEED_A      = A_OFF_NB + NB_BYTES;

    // Tier B: single G + bf16x3 fp32-input GEMM per batch (~54.6 MB)
    const size_t B_OFF_CAND2 = G_BYTES;
    const size_t B_OFF_IDX   = B_OFF_CAND2 + CAND2_BYTES;
    const size_t B_OFF_ST    = B_OFF_IDX + IDX_BYTES;
    const size_t B_OFF_CT    = B_OFF_ST + ST_BYTES;
    const size_t B_OFF_NA    = B_OFF_CT + CT_BYTES;
    const size_t B_OFF_NB    = B_OFF_NA + NA_BYTES;
    const size_t NEED_B      = B_OFF_NB + NB_BYTES;
    (void)NEED_B;

    if (ws_size >= NEED_A) {
        unsigned short* G4 = (unsigned short*)d_ws;
        u64* cand2      = (u64*)((char*)d_ws + A_OFF_CAND2);
        int* idx        = (int*)((char*)d_ws + A_OFF_IDX);
        float* style_t  = (float*)((char*)d_ws + A_OFF_ST);
        float* content_t = (float*)((char*)d_ws + A_OFF_CT);
        unsigned short* PS = (unsigned short*)((char*)d_ws + A_OFF_PS);
        unsigned short* PC = (unsigned short*)((char*)d_ws + A_OFF_PC);
        float* na_c     = (float*)((char*)d_ws + A_OFF_NA);
        float* nb_s     = (float*)((char*)d_ws + A_OFF_NB);

        transpose_b<<<dim3(128, 8, 1), 256, 0, stream>>>(style, style_t);
        transpose_b<<<dim3(128, 8, 4), 256, 0, stream>>>(content, content_t);
        col_norms<<<dim3(80), 256, 0, stream>>>(content, style, na_c, nb_s);
        panels_f16<<<dim3(32, 8, 1), 256, 0, stream>>>(style, PS);
        panels_f16<<<dim3(32, 8, 4), 256, 0, stream>>>(content, PC);
        g_gemm_f16<<<dim3(32, 32, 4), 256, 0, stream>>>(PC, PS, G4);
        stencil_ilp<<<dim3(NP / 4, 4), 256, 0, stream>>>(G4, enc_bias, cand2, 0);
        rescore6<<<dim3(4 * NP), 128, 0, stream>>>(
            content_t, style_t, enc_bias, G4, na_c, nb_s, cand2, idx, 0);
        produce_out2<<<dim3(4 * 64, 2), 256, 0, stream>>>(
            style_t, dec_bias, intra_bias, idx, out);
    } else {
        unsigned short* Gb = (unsigned short*)d_ws;
        u64* cand2      = (u64*)((char*)d_ws + B_OFF_CAND2);
        int* idx        = (int*)((char*)d_ws + B_OFF_IDX);
        float* style_t  = (float*)((char*)d_ws + B_OFF_ST);
        float* content_t = (float*)((char*)d_ws + B_OFF_CT);
        float* na_c     = (float*)((char*)d_ws + B_OFF_NA);
        float* nb_s     = (float*)((char*)d_ws + B_OFF_NB);

        transpose_b<<<dim3(128, 8, 1), 256, 0, stream>>>(style, style_t);
        transpose_b<<<dim3(128, 8, 4), 256, 0, stream>>>(content, content_t);
        col_norms<<<dim3(80), 256, 0, stream>>>(content, style, na_c, nb_s);
        for (int b = 0; b < 4; ++b) {
            g_gemm<<<dim3(32, 32), 256, 0, stream>>>(
                content + (size_t)b * NCSP, style, Gb);
            stencil_ilp<<<dim3(NP / 4, 1), 256, 0, stream>>>(Gb, enc_bias, cand2, b);
            rescore6<<<dim3(NP), 128, 0, stream>>>(
                content_t, style_t, enc_bias, Gb, na_c, nb_s, cand2, idx, b);
        }
        produce_out2<<<dim3(4 * 64, 2), 256, 0, stream>>>(
            style_t, dec_bias, intra_bias, idx, out);
    }
}